// Round 11
// baseline (784.945 us; speedup 1.0000x reference)
//
#include <hip/hip_runtime.h>
#include <hip/hip_fp16.h>

// Problem constants (from reference)
#define NN  100000   // nodes
#define FIN 128      // in features
#define HID 256      // hidden
#define NE  600000   // edges
#define FEPS 1e-12f
#define SRCMASK 0x03FFFFFFu   // col layout: bits 0..25 src, bits 26..31 dst&63

// ---------------------------------------------------------------------------
// Workspace layout (~31.1 MB):
//   float Wt[256*256] | half xh[NN*FIN] | int cnt[NN] | cur[NN] | off[NN+1]
//   | col[NE] | float g[NN*2] | r[NN*2] | int bsum[128] | flag[1]
// Evidence log:
//  - R5: ws_size >= 31.1 MB (fast path ran); bf16 FEATURES fail precision
//    (0.465 via 1/||z|| amplification); fp16 OK (R9 absmax 0.0156 vs 0.0327).
//  - R6: wave-per-node gather REGRESSED (too little MLP per wave).
//  - R7/R8: occupancy 16->32 waves/CU: 507->309->291 us. Lever exhausted.
//  - R9: fp16 gather: FETCH 170->100 MB but only 291->273 us => gather is
//    LATENCY-bound by per-node loop structure (degree skew), not bytes.
//  - R10: edge-parallel + __shfl binary search FAILED (absmax 1.4); audit
//    found no logic error; suspect __shfl under divergent exec. R11: same
//    idea with dst&63 PACKED into col bits 26..31 (no shfl, no search).
// ---------------------------------------------------------------------------

__device__ __forceinline__ int clampN(int v) {
    return ((unsigned)v < (unsigned)NN) ? v : 0;
}
__device__ __forceinline__ int ld_src(const int* ei, int e, int f) {
    return f ? ei[2 * e] : ei[e];
}
__device__ __forceinline__ int ld_dst(const int* ei, int e, int f) {
    return f ? ei[2 * (NE + e)] : ei[NE + e];
}

// ---------------------------------------------------------------------------
// Setup (fused): block 0 = int64/int32 detect; blocks 1..256 = weight
// transpose; blocks 257.. = x fp32 -> fp16 (RNE); all blocks zero cnt|cur.
// ---------------------------------------------------------------------------
__global__ __launch_bounds__(256) void setup_kernel(
    const int* __restrict__ ei,
    const float* __restrict__ x,
    const float* __restrict__ W1l, const float* __restrict__ W1r,
    float* __restrict__ Wt, __half* __restrict__ xh,
    int* __restrict__ cnt2 /* cnt|cur, 2*NN */, int* __restrict__ flag)
{
    int b = blockIdx.x;
    int t = threadIdx.x;
    if (b == 0) {
        if (t < 64) {
            // int64 little-endian (<2^31): every odd 32-bit word is 0.
            unsigned long long bal = __ballot(ei[2 * t + 1] != 0);
            if (t == 0) *flag = (bal == 0ULL) ? 1 : 0;
        }
    } else if (b <= 256) {
        int k2 = b - 1;
        float v = (k2 < FIN) ? W1l[(size_t)t * FIN + k2]
                             : W1r[(size_t)t * FIN + (k2 - FIN)];
        Wt[(size_t)k2 * HID + t] = v;
    } else {
        int idx = (b - 257) * 256 + t;           // 8-float group
        if (idx < NN * FIN / 8) {
            const float4* px = (const float4*)(x + (size_t)idx * 8);
            float4 v0 = px[0], v1 = px[1];
            __half2 h0 = __float22half2_rn(make_float2(v0.x, v0.y));
            __half2 h1 = __float22half2_rn(make_float2(v0.z, v0.w));
            __half2 h2 = __float22half2_rn(make_float2(v1.x, v1.y));
            __half2 h3 = __float22half2_rn(make_float2(v1.z, v1.w));
            uint4 u;
            u.x = __builtin_bit_cast(unsigned, h0);
            u.y = __builtin_bit_cast(unsigned, h1);
            u.z = __builtin_bit_cast(unsigned, h2);
            u.w = __builtin_bit_cast(unsigned, h3);
            ((uint4*)xh)[idx] = u;
        }
    }
    for (int idx = b * 256 + t; idx < 2 * NN; idx += gridDim.x * 256)
        cnt2[idx] = 0;
}

// in-degree count
__global__ __launch_bounds__(256) void count_kernel(
    const int* __restrict__ ei, const int* __restrict__ flag,
    int* __restrict__ cnt)
{
    int e = blockIdx.x * 256 + threadIdx.x;
    if (e >= NE) return;
    int f = *flag;
    atomicAdd(cnt + clampN(ld_dst(ei, e, f)), 1);
}

// 3-phase parallel exclusive scan of cnt[NN] -> off[NN+1]
__global__ __launch_bounds__(1024) void scan_a_kernel(
    const int* __restrict__ cnt, int* __restrict__ off, int* __restrict__ bsum)
{
    __shared__ int sm[1024];
    int t = threadIdx.x;
    int idx = blockIdx.x * 1024 + t;
    int v = (idx < NN) ? cnt[idx] : 0;
    sm[t] = v;
    __syncthreads();
    for (int d = 1; d < 1024; d <<= 1) {
        int w = (t >= d) ? sm[t - d] : 0;
        __syncthreads();
        sm[t] += w;
        __syncthreads();
    }
    if (idx < NN) off[idx] = sm[t] - v;
    if (t == 1023) bsum[blockIdx.x] = sm[1023];
}
__global__ __launch_bounds__(128) void scan_b_kernel(
    int* __restrict__ bsum, int* __restrict__ off, int nblocks)
{
    __shared__ int sm[128];
    int t = threadIdx.x;
    int v = (t < nblocks) ? bsum[t] : 0;
    sm[t] = v;
    __syncthreads();
    for (int d = 1; d < 128; d <<= 1) {
        int w = (t >= d) ? sm[t - d] : 0;
        __syncthreads();
        sm[t] += w;
        __syncthreads();
    }
    if (t < nblocks) bsum[t] = sm[t] - v;
    if (t == 0) off[NN] = NE;
}
__global__ __launch_bounds__(1024) void scan_c_kernel(
    const int* __restrict__ bsum, int* __restrict__ off)
{
    int idx = blockIdx.x * 1024 + threadIdx.x;
    if (idx < NN) off[idx] += bsum[blockIdx.x];
}

// place packed (dst&63)<<26 | src into CSR slots
__global__ __launch_bounds__(256) void fill_kernel(
    const int* __restrict__ ei, const int* __restrict__ flag,
    const int* __restrict__ off, int* __restrict__ cur, int* __restrict__ col)
{
    int e = blockIdx.x * 256 + threadIdx.x;
    if (e >= NE) return;
    int f = *flag;
    int src = clampN(ld_src(ei, e, f));
    int dst = clampN(ld_dst(ei, e, f));
    int p = atomicAdd(cur + dst, 1);
    col[off[dst] + p] = (int)(((unsigned)(dst & 63) << 26) | (unsigned)src);
}

// ---------------------------------------------------------------------------
// Fused layer-1 (+ layer-2 projections), LDS-tiled fp32 GEMM.
// 1024 threads/block, 64 nodes/block, 64 KB tile -> 2 blocks/CU = 32 waves/CU.
// LDS tile: element (f, n) at smem_f[f*64 + (n ^ ((f>>3)&31))].
// Phase A (HALFX, R11): EDGE-PARALLEL gather, search-free. Block's edges are
//   the contiguous col range [off[nb], off[nb+64]); each edge's local dst is
//   packed in col bits 26..31 (nb is 64-aligned => dst&63 == dst-nb).
//   Work item = (edge, 16B fp16 chunk); guarded pairs -> 2 independent loads
//   in flight/thread; accumulate via LDS atomicAdd; scale by 1/deg after.
//   No __shfl, no LDS table, no divergence-sensitive cross-lane ops.
// Phase B: 16 waves; wave w owns j-strip [16w,16w+16); o[16] in VGPRs;
//   weight rows wave-uniform -> scalar loads; lane = node.
// Epilogue: bias/relu/L2-norm partials -> LDS overlay -> final g,r.
// ---------------------------------------------------------------------------
template <bool HALFX>
__global__ __launch_bounds__(1024, 8) void layer1_kernel(
    const int* __restrict__ off, const int* __restrict__ col,
    const float* __restrict__ x,    // [NN, FIN] fp32
    const __half* __restrict__ xh,  // [NN, FIN] fp16 copy (HALFX path)
    const float* __restrict__ Wt,   // [256, HID]
    const float* __restrict__ b1,
    const float* __restrict__ W2l, const float* __restrict__ W2r,
    float* __restrict__ g, float* __restrict__ r)
{
    __shared__ float smem_f[256 * 64];   // 64 KB

    const int t  = threadIdx.x;          // 0..1023
    const int nb = blockIdx.x * 64;
    const int l  = t & 63;               // lane

    if (HALFX) {
        // ---- Phase A: edge-parallel gather with LDS atomics ----
        // zero agg rows [0,128)
#pragma unroll
        for (int i = 0; i < 8; ++i) smem_f[t + 1024 * i] = 0.0f;
        // stage self rows [128,256) from fp32 x (exact)
        {
            const int n_loc = t >> 4;
            const int ft    = t & 15;
            const int n     = nb + n_loc;
            const bool valid = (n < NN);
            const float4* sp = (const float4*)(x + (size_t)(valid ? n : 0) * FIN + ft * 8);
            float4 s0v = valid ? sp[0] : make_float4(0.f, 0.f, 0.f, 0.f);
            float4 s1v = valid ? sp[1] : make_float4(0.f, 0.f, 0.f, 0.f);
            float sv[8] = {s0v.x, s0v.y, s0v.z, s0v.w, s1v.x, s1v.y, s1v.z, s1v.w};
#pragma unroll
            for (int k = 0; k < 8; ++k) {
                int f = FIN + ft * 8 + k;
                smem_f[f * 64 + (n_loc ^ ((f >> 3) & 31))] = sv[k];
            }
        }
        __syncthreads();

        const int e0    = off[nb];                         // uniform
        const int eE    = off[(nb + 64 < NN) ? nb + 64 : NN];
        const int items = (eE - e0) * 16;

        for (int i = t; i < items; i += 2048) {            // guarded pair
            int i2 = i + 1024;
            bool has2 = (i2 < items);
            unsigned p1 = (unsigned)col[e0 + (i >> 4)];
            unsigned p2 = has2 ? (unsigned)col[e0 + (i2 >> 4)] : 0u;
            int ft1 = i & 15, ft2 = i2 & 15;
            int s1c = clampN((int)(p1 & SRCMASK));
            int s2c = clampN((int)(p2 & SRCMASK));
            uint4 v1 = *(const uint4*)(xh + (size_t)s1c * FIN + ft1 * 8);
            uint4 v2 = has2 ? *(const uint4*)(xh + (size_t)s2c * FIN + ft2 * 8)
                            : make_uint4(0, 0, 0, 0);
            int nc1 = (int)(p1 >> 26) ^ ft1;
            int nc2 = (int)(p2 >> 26) ^ ft2;
#pragma unroll
            for (int u = 0; u < 4; ++u) {
                float2 f2 = __half22float2(__builtin_bit_cast(__half2, (&v1.x)[u]));
                atomicAdd(&smem_f[(ft1 * 8 + 2 * u)     * 64 + nc1], f2.x);
                atomicAdd(&smem_f[(ft1 * 8 + 2 * u + 1) * 64 + nc1], f2.y);
            }
            if (has2) {
#pragma unroll
                for (int u = 0; u < 4; ++u) {
                    float2 f2 = __half22float2(__builtin_bit_cast(__half2, (&v2.x)[u]));
                    atomicAdd(&smem_f[(ft2 * 8 + 2 * u)     * 64 + nc2], f2.x);
                    atomicAdd(&smem_f[(ft2 * 8 + 2 * u + 1) * 64 + nc2], f2.y);
                }
            }
        }
        __syncthreads();

        // scale agg rows by 1/deg (degrees from global off, L2-hot)
        {
            const int n_loc = t >> 4;
            const int ft    = t & 15;
            int na = nb + n_loc;     if (na > NN) na = NN;
            int nbb = nb + n_loc + 1; if (nbb > NN) nbb = NN;
            float ic = 1.0f / fmaxf((float)(off[nbb] - off[na]), 1.0f);
            int nc = n_loc ^ ft;
#pragma unroll
            for (int k = 0; k < 8; ++k)
                smem_f[(ft * 8 + k) * 64 + nc] *= ic;
        }
    } else {
        // ---- Fallback: R8 per-node fp32 gather (col masked) ----
        const int n_loc = t >> 4;
        const int ft    = t & 15;
        const int fbase = ft * 8;
        const int n     = nb + n_loc;
        const bool valid = (n < NN);

        float a[8];
#pragma unroll
        for (int i = 0; i < 8; ++i) a[i] = 0.0f;

        int s0 = 0, s1 = 0;
        if (valid) { s0 = off[n]; s1 = off[n + 1]; }
        int i = s0;
        for (; i + 3 < s1; i += 4) {
            int c0 = clampN((int)((unsigned)col[i]     & SRCMASK));
            int c1 = clampN((int)((unsigned)col[i + 1] & SRCMASK));
            int c2 = clampN((int)((unsigned)col[i + 2] & SRCMASK));
            int c3 = clampN((int)((unsigned)col[i + 3] & SRCMASK));
            const float4* p0 = (const float4*)(x + (size_t)c0 * FIN + fbase);
            const float4* p1 = (const float4*)(x + (size_t)c1 * FIN + fbase);
            const float4* p2 = (const float4*)(x + (size_t)c2 * FIN + fbase);
            const float4* p3 = (const float4*)(x + (size_t)c3 * FIN + fbase);
            float4 v00 = p0[0], v01 = p0[1];
            float4 v10 = p1[0], v11 = p1[1];
            float4 v20 = p2[0], v21 = p2[1];
            float4 v30 = p3[0], v31 = p3[1];
            a[0] += (v00.x + v10.x) + (v20.x + v30.x);
            a[1] += (v00.y + v10.y) + (v20.y + v30.y);
            a[2] += (v00.z + v10.z) + (v20.z + v30.z);
            a[3] += (v00.w + v10.w) + (v20.w + v30.w);
            a[4] += (v01.x + v11.x) + (v21.x + v31.x);
            a[5] += (v01.y + v11.y) + (v21.y + v31.y);
            a[6] += (v01.z + v11.z) + (v21.z + v31.z);
            a[7] += (v01.w + v11.w) + (v21.w + v31.w);
        }
        for (; i < s1; ++i) {
            int c0 = clampN((int)((unsigned)col[i] & SRCMASK));
            const float4* p0 = (const float4*)(x + (size_t)c0 * FIN + fbase);
            float4 v00 = p0[0], v01 = p0[1];
            a[0] += v00.x; a[1] += v00.y; a[2] += v00.z; a[3] += v00.w;
            a[4] += v01.x; a[5] += v01.y; a[6] += v01.z; a[7] += v01.w;
        }
        float ic = 1.0f / fmaxf((float)(s1 - s0), 1.0f);
#pragma unroll
        for (int k = 0; k < 8; ++k) {
            int f = fbase + k;
            smem_f[f * 64 + (n_loc ^ ((f >> 3) & 31))] = a[k] * ic;
        }
        const float4* sp = (const float4*)(x + (size_t)(valid ? n : 0) * FIN + fbase);
        float4 s0v = valid ? sp[0] : make_float4(0.f, 0.f, 0.f, 0.f);
        float4 s1v = valid ? sp[1] : make_float4(0.f, 0.f, 0.f, 0.f);
        float sv[8] = {s0v.x, s0v.y, s0v.z, s0v.w, s1v.x, s1v.y, s1v.z, s1v.w};
#pragma unroll
        for (int k = 0; k < 8; ++k) {
            int f = FIN + fbase + k;
            smem_f[f * 64 + (n_loc ^ ((f >> 3) & 31))] = sv[k];
        }
    }
    __syncthreads();

    // ---- Phase B: 16 waves, wave w owns j in [16w, 16w+16); lane = node ----
    const int w  = __builtin_amdgcn_readfirstlane(t >> 6);  // 0..15
    const int jb = w * 16;

    float o[16];
#pragma unroll
    for (int i = 0; i < 16; ++i) o[i] = 0.0f;

#pragma unroll 1
    for (int k2 = 0; k2 < 2 * FIN; ++k2) {
        float av = smem_f[k2 * 64 + (l ^ ((k2 >> 3) & 31))];
        const float* wrow = Wt + (size_t)k2 * HID + jb;   // wave-uniform
#pragma unroll
        for (int i = 0; i < 16; ++i) o[i] += av * wrow[i];
    }

    // ---- Epilogue: bias, relu, partials over this wave's 16 j's ----
    float sq = 0.f, g0 = 0.f, g1 = 0.f, r0 = 0.f, r1 = 0.f;
    const float* b1w  = b1  + jb;
    const float* w2la = W2l + jb;
    const float* w2lb = W2l + HID + jb;
    const float* w2ra = W2r + jb;
    const float* w2rb = W2r + HID + jb;
#pragma unroll
    for (int i = 0; i < 16; ++i) {
        float oo = o[i] + b1w[i];
        sq += oo * oo;
        float p = fmaxf(oo, 0.0f);           // relu(o/D) = relu(o)/D
        g0 += p * w2la[i];
        g1 += p * w2lb[i];
        r0 += p * w2ra[i];
        r1 += p * w2rb[i];
    }

    __syncthreads();                          // tile dead; reuse as overlay
    smem_f[0 * 1024 + t] = sq;
    smem_f[1 * 1024 + t] = g0;
    smem_f[2 * 1024 + t] = g1;
    smem_f[3 * 1024 + t] = r0;
    smem_f[4 * 1024 + t] = r1;
    __syncthreads();

    if (t < 64) {
        int n2 = nb + t;
        float sqs = 0.f, G0 = 0.f, G1 = 0.f, R0 = 0.f, R1 = 0.f;
#pragma unroll
        for (int ww = 0; ww < 16; ++ww) {
            sqs += smem_f[0 * 1024 + ww * 64 + t];
            G0  += smem_f[1 * 1024 + ww * 64 + t];
            G1  += smem_f[2 * 1024 + ww * 64 + t];
            R0  += smem_f[3 * 1024 + ww * 64 + t];
            R1  += smem_f[4 * 1024 + ww * 64 + t];
        }
        float inv = 1.0f / fmaxf(sqrtf(sqs), FEPS);
        if (n2 < NN) {
            g[2 * (size_t)n2]     = G0 * inv;
            g[2 * (size_t)n2 + 1] = G1 * inv;
            r[2 * (size_t)n2]     = R0 * inv;
            r[2 * (size_t)n2 + 1] = R1 * inv;
        }
    }
}

// layer-2 mean via CSR gather of g, +b2, +lin_r, L2-normalize, log_softmax
__global__ __launch_bounds__(256) void finalize_kernel(
    const int* __restrict__ off, const int* __restrict__ col,
    const float* __restrict__ g, const float* __restrict__ r,
    const float* __restrict__ b2,
    float* __restrict__ out)
{
    int n = blockIdx.x * 256 + threadIdx.x;
    if (n >= NN) return;
    int s0 = off[n], s1 = off[n + 1];
    float z0 = 0.0f, z1 = 0.0f, y0b = 0.0f, y1b = 0.0f;
    int i = s0;
    for (; i + 1 < s1; i += 2) {
        int sa = clampN((int)((unsigned)col[i]     & SRCMASK));
        int sb = clampN((int)((unsigned)col[i + 1] & SRCMASK));
        float2 va = *(const float2*)(g + 2 * (size_t)sa);
        float2 vb = *(const float2*)(g + 2 * (size_t)sb);
        z0 += va.x; z1 += va.y;
        y0b += vb.x; y1b += vb.y;
    }
    if (i < s1) {
        int sa = clampN((int)((unsigned)col[i] & SRCMASK));
        float2 va = *(const float2*)(g + 2 * (size_t)sa);
        z0 += va.x; z1 += va.y;
    }
    z0 += y0b; z1 += y1b;
    float ic = 1.0f / fmaxf((float)(s1 - s0), 1.0f);
    z0 = z0 * ic + b2[0] + r[2 * (size_t)n];
    z1 = z1 * ic + b2[1] + r[2 * (size_t)n + 1];
    float d = 1.0f / fmaxf(sqrtf(z0 * z0 + z1 * z1), FEPS);
    float y0 = z0 * d, y1 = z1 * d;
    float m = fmaxf(y0, y1);
    float l = m + logf(__expf(y0 - m) + __expf(y1 - m));
    out[2 * (size_t)n]     = y0 - l;
    out[2 * (size_t)n + 1] = y1 - l;
}

// ---------------------------------------------------------------------------
extern "C" void kernel_launch(void* const* d_in, const int* in_sizes, int n_in,
                              void* d_out, int out_size, void* d_ws, size_t ws_size,
                              hipStream_t stream) {
    // setup_inputs order: x, edge_index, W1_l, b1, W1_r, W2_l, b2, W2_r
    const float* x   = (const float*)d_in[0];
    const int*   ei  = (const int*)d_in[1];
    const float* W1l = (const float*)d_in[2];
    const float* b1  = (const float*)d_in[3];
    const float* W1r = (const float*)d_in[4];
    const float* W2l = (const float*)d_in[5];
    const float* b2  = (const float*)d_in[6];
    const float* W2r = (const float*)d_in[7];

    const int nsb = (NN + 1023) / 1024;          // 98 scan blocks
    const int ncv = (NN * FIN / 8 + 255) / 256;  // convert blocks

    char* p = (char*)d_ws;
    float* Wt = (float*)p;                p += (size_t)256 * 256 * 4;

    size_t need_fast = (size_t)256 * 256 * 4 + (size_t)NN * FIN * 2 +
                       ((size_t)2 * NN + (NN + 1) + NE + 4 * NN + 128 + 1) * 4;
    bool fast = (ws_size >= need_fast);   // host-side constant: graph-safe

    __half* xh = nullptr;
    if (fast) { xh = (__half*)p; p += (size_t)NN * FIN * 2; }

    int*   cnt  = (int*)p;
    int*   cur  = cnt + NN;
    int*   off  = cur + NN;                      // NN+1
    int*   col  = off + NN + 1;                  // NE
    float* g    = (float*)(col + NE);            // NN*2
    float* r    = g + 2 * (size_t)NN;            // NN*2
    int*   bsum = (int*)(r + 2 * (size_t)NN);    // 128
    int*   flag = bsum + 128;

    int eb = (NE + 255) / 256;
    setup_kernel<<<fast ? (257 + ncv) : 257, 256, 0, stream>>>(
        ei, x, W1l, W1r, Wt, xh, cnt, flag);
    count_kernel<<<eb, 256, 0, stream>>>(ei, flag, cnt);
    scan_a_kernel<<<nsb, 1024, 0, stream>>>(cnt, off, bsum);
    scan_b_kernel<<<1, 128, 0, stream>>>(bsum, off, nsb);
    scan_c_kernel<<<nsb, 1024, 0, stream>>>(bsum, off);
    fill_kernel<<<eb, 256, 0, stream>>>(ei, flag, off, cur, col);
    if (fast)
        layer1_kernel<true><<<(NN + 63) / 64, 1024, 0, stream>>>(
            off, col, x, xh, Wt, b1, W2l, W2r, g, r);
    else
        layer1_kernel<false><<<(NN + 63) / 64, 1024, 0, stream>>>(
            off, col, x, xh, Wt, b1, W2l, W2r, g, r);
    finalize_kernel<<<(NN + 255) / 256, 256, 0, stream>>>(off, col, g, r, b2,
                                                          (float*)d_out);
}

// Round 12
// 432.669 us; speedup vs baseline: 1.8142x; 1.8142x over previous
//
#include <hip/hip_runtime.h>
#include <hip/hip_fp16.h>

// Problem constants (from reference)
#define NN  100000   // nodes
#define FIN 128      // in features
#define HID 256      // hidden
#define NE  600000   // edges
#define FEPS 1e-12f

// ---------------------------------------------------------------------------
// Workspace layout (~31.1 MB):
//   float Wt[256*256] | half xh[NN*FIN] | int cnt[NN] | cur[NN] | off[NN+1]
//   | col[NE] | float g[NN*2] | r[NN*2] | int bsum[128]
// Evidence log:
//  - R5: ws_size >= 31.1 MB (fast path ran); bf16 FEATURES fail precision
//    (0.465 via 1/||z|| amplification); fp16 OK (R9 absmax 0.0156 vs 0.0327).
//  - R6: wave-per-node gather REGRESSED (too little MLP per wave).
//  - R7/R8: occupancy 16->32 waves/CU: 507->309->291 us. Lever exhausted.
//  - R9: fp16 gather: FETCH 170->100 MB, 291->273 us => latency-bound by
//    per-node round count, not bytes. BEST VERIFIED: 428 us total.
//  - R10: edge-parallel + __shfl search FAILED (divergent-exec shfl).
//  - R11: edge-parallel + LDS fp32 atomics 3x SLOW (CAS codegen suspected).
//    => stay thread-per-(node,ft); attack ROUND COUNT with guarded 8-wide.
// ---------------------------------------------------------------------------

__device__ __forceinline__ int clampN(int v) {
    return ((unsigned)v < (unsigned)NN) ? v : 0;
}
// int64 vs int32 edge_index: little-endian int64 (<2^31) => odd words all 0.
// 4 words: P(false positive | int32) ~ 1e-20. Uniform -> scalarized loads.
__device__ __forceinline__ int detect4(const int* ei) {
    return ((ei[1] | ei[3] | ei[5] | ei[7]) == 0) ? 1 : 0;
}
__device__ __forceinline__ int ld_src(const int* ei, int e, int f) {
    return f ? ei[2 * e] : ei[e];
}
__device__ __forceinline__ int ld_dst(const int* ei, int e, int f) {
    return f ? ei[2 * (NE + e)] : ei[NE + e];
}

// unpack one 16B fp16 chunk (8 halves) and masked-accumulate into a[8]
__device__ __forceinline__ void acc_chunk(float* a, const uint4& v, float m) {
#pragma unroll
    for (int u = 0; u < 4; ++u) {
        float2 f = __half22float2(__builtin_bit_cast(__half2, (&v.x)[u]));
        a[2 * u]     += m * f.x;
        a[2 * u + 1] += m * f.y;
    }
}

// ---------------------------------------------------------------------------
// Setup (fused): blocks [0,256) weight transpose; [256,256+ncv) x->fp16;
// [256+ncv, ...) in-degree count (cnt pre-zeroed by memset).
// ---------------------------------------------------------------------------
__global__ __launch_bounds__(256) void setup_kernel(
    const int* __restrict__ ei,
    const float* __restrict__ x,
    const float* __restrict__ W1l, const float* __restrict__ W1r,
    float* __restrict__ Wt, __half* __restrict__ xh,
    int* __restrict__ cnt, int ncv)
{
    int b = blockIdx.x;
    int t = threadIdx.x;
    if (b < 256) {
        int k2 = b;
        float v = (k2 < FIN) ? W1l[(size_t)t * FIN + k2]
                             : W1r[(size_t)t * FIN + (k2 - FIN)];
        Wt[(size_t)k2 * HID + t] = v;
    } else if (b < 256 + ncv) {
        int idx = (b - 256) * 256 + t;           // 8-float group
        if (idx < NN * FIN / 8) {
            const float4* px = (const float4*)(x + (size_t)idx * 8);
            float4 v0 = px[0], v1 = px[1];
            __half2 h0 = __float22half2_rn(make_float2(v0.x, v0.y));
            __half2 h1 = __float22half2_rn(make_float2(v0.z, v0.w));
            __half2 h2 = __float22half2_rn(make_float2(v1.x, v1.y));
            __half2 h3 = __float22half2_rn(make_float2(v1.z, v1.w));
            uint4 u;
            u.x = __builtin_bit_cast(unsigned, h0);
            u.y = __builtin_bit_cast(unsigned, h1);
            u.z = __builtin_bit_cast(unsigned, h2);
            u.w = __builtin_bit_cast(unsigned, h3);
            ((uint4*)xh)[idx] = u;
        }
    } else {
        int e = (b - 256 - ncv) * 256 + t;
        if (e < NE) {
            int f = detect4(ei);
            atomicAdd(cnt + clampN(ld_dst(ei, e, f)), 1);
        }
    }
}

// 3-phase parallel exclusive scan of cnt[NN] -> off[NN+1]
__global__ __launch_bounds__(1024) void scan_a_kernel(
    const int* __restrict__ cnt, int* __restrict__ off, int* __restrict__ bsum)
{
    __shared__ int sm[1024];
    int t = threadIdx.x;
    int idx = blockIdx.x * 1024 + t;
    int v = (idx < NN) ? cnt[idx] : 0;
    sm[t] = v;
    __syncthreads();
    for (int d = 1; d < 1024; d <<= 1) {
        int w = (t >= d) ? sm[t - d] : 0;
        __syncthreads();
        sm[t] += w;
        __syncthreads();
    }
    if (idx < NN) off[idx] = sm[t] - v;
    if (t == 1023) bsum[blockIdx.x] = sm[1023];
}
__global__ __launch_bounds__(128) void scan_b_kernel(
    int* __restrict__ bsum, int* __restrict__ off, int nblocks)
{
    __shared__ int sm[128];
    int t = threadIdx.x;
    int v = (t < nblocks) ? bsum[t] : 0;
    sm[t] = v;
    __syncthreads();
    for (int d = 1; d < 128; d <<= 1) {
        int w = (t >= d) ? sm[t - d] : 0;
        __syncthreads();
        sm[t] += w;
        __syncthreads();
    }
    if (t < nblocks) bsum[t] = sm[t] - v;
    if (t == 0) off[NN] = NE;
}
__global__ __launch_bounds__(1024) void scan_c_kernel(
    const int* __restrict__ bsum, int* __restrict__ off)
{
    int idx = blockIdx.x * 1024 + threadIdx.x;
    if (idx < NN) off[idx] += bsum[blockIdx.x];
}

// place src ids into CSR slots
__global__ __launch_bounds__(256) void fill_kernel(
    const int* __restrict__ ei,
    const int* __restrict__ off, int* __restrict__ cur, int* __restrict__ col)
{
    int e = blockIdx.x * 256 + threadIdx.x;
    if (e >= NE) return;
    int f = detect4(ei);
    int src = clampN(ld_src(ei, e, f));
    int dst = clampN(ld_dst(ei, e, f));
    int p = atomicAdd(cur + dst, 1);
    col[off[dst] + p] = src;
}

// ---------------------------------------------------------------------------
// Fused layer-1 (+ layer-2 projections), LDS-tiled fp32 GEMM.
// 1024 threads/block, 64 nodes/block, 64 KB tile -> 2 blocks/CU = 32 waves/CU.
// LDS tile: element (f, n) at smem_f[f*64 + (n ^ ((f>>3)&31))].
// Phase A (HALFX, R12): 16 threads/node, 8 features each; ONE guarded 8-wide
//   batch per round: 8 clamped col reads + 8 independent 16B xh loads issued
//   together, masked fma accumulate (mask 0 lanes re-read last row: L1-hot).
//   Typical node (d<=8): ONE round. Max node in block (~16): 2 rounds
//   (R9's 4-wide + scalar tail needed 5-6 -> barrier time halves).
// Phase B: 16 waves; wave w owns j-strip [16w,16w+16); o[16] in VGPRs;
//   weight rows wave-uniform -> scalar loads; lane = node.
// Epilogue: bias/relu/L2-norm partials -> LDS overlay -> final g,r.
// ---------------------------------------------------------------------------
template <bool HALFX>
__global__ __launch_bounds__(1024, 8) void layer1_kernel(
    const int* __restrict__ off, const int* __restrict__ col,
    const float* __restrict__ x,    // [NN, FIN] fp32
    const __half* __restrict__ xh,  // [NN, FIN] fp16 copy (HALFX path)
    const float* __restrict__ Wt,   // [256, HID]
    const float* __restrict__ b1,
    const float* __restrict__ W2l, const float* __restrict__ W2r,
    float* __restrict__ g, float* __restrict__ r)
{
    __shared__ float smem_f[256 * 64];   // 64 KB

    const int t  = threadIdx.x;          // 0..1023
    const int nb = blockIdx.x * 64;
    const int l  = t & 63;               // lane

    // ---- Phase A: thread-parallel gather/mean ----
    {
        const int n_loc = t >> 4;        // 0..63
        const int ft    = t & 15;        // feature group (8 floats)
        const int fbase = ft * 8;
        const int n     = nb + n_loc;
        const bool valid = (n < NN);

        float a[8];
#pragma unroll
        for (int i = 0; i < 8; ++i) a[i] = 0.0f;

        int s0 = 0, s1 = 0;
        if (valid) { s0 = off[n]; s1 = off[n + 1]; }

        if (HALFX) {
            for (int base = s0; base < s1; base += 8) {
                int rm = s1 - base - 1;          // >= 0
                int c0 = clampN(col[base]);
                int c1 = clampN(col[base + min(1, rm)]);
                int c2 = clampN(col[base + min(2, rm)]);
                int c3 = clampN(col[base + min(3, rm)]);
                int c4 = clampN(col[base + min(4, rm)]);
                int c5 = clampN(col[base + min(5, rm)]);
                int c6 = clampN(col[base + min(6, rm)]);
                int c7 = clampN(col[base + min(7, rm)]);
                uint4 v0 = *(const uint4*)(xh + (size_t)c0 * FIN + fbase);
                uint4 v1 = *(const uint4*)(xh + (size_t)c1 * FIN + fbase);
                uint4 v2 = *(const uint4*)(xh + (size_t)c2 * FIN + fbase);
                uint4 v3 = *(const uint4*)(xh + (size_t)c3 * FIN + fbase);
                uint4 v4 = *(const uint4*)(xh + (size_t)c4 * FIN + fbase);
                uint4 v5 = *(const uint4*)(xh + (size_t)c5 * FIN + fbase);
                uint4 v6 = *(const uint4*)(xh + (size_t)c6 * FIN + fbase);
                uint4 v7 = *(const uint4*)(xh + (size_t)c7 * FIN + fbase);
                acc_chunk(a, v0, 1.0f);
                acc_chunk(a, v1, (rm >= 1) ? 1.0f : 0.0f);
                acc_chunk(a, v2, (rm >= 2) ? 1.0f : 0.0f);
                acc_chunk(a, v3, (rm >= 3) ? 1.0f : 0.0f);
                acc_chunk(a, v4, (rm >= 4) ? 1.0f : 0.0f);
                acc_chunk(a, v5, (rm >= 5) ? 1.0f : 0.0f);
                acc_chunk(a, v6, (rm >= 6) ? 1.0f : 0.0f);
                acc_chunk(a, v7, (rm >= 7) ? 1.0f : 0.0f);
            }
        } else {
            for (int i = s0; i < s1; ++i) {
                int c0 = clampN(col[i]);
                const float4* p0 = (const float4*)(x + (size_t)c0 * FIN + fbase);
                float4 v00 = p0[0], v01 = p0[1];
                a[0] += v00.x; a[1] += v00.y; a[2] += v00.z; a[3] += v00.w;
                a[4] += v01.x; a[5] += v01.y; a[6] += v01.z; a[7] += v01.w;
            }
        }
        float ic = 1.0f / fmaxf((float)(s1 - s0), 1.0f);
#pragma unroll
        for (int k = 0; k < 8; ++k) {
            int f = fbase + k;
            smem_f[f * 64 + (n_loc ^ ((f >> 3) & 31))] = a[k] * ic;
        }
        // self row: fp32 source (exact), coalesced
        const float4* sp = (const float4*)(x + (size_t)(valid ? n : 0) * FIN + fbase);
        float4 s0v = valid ? sp[0] : make_float4(0.f, 0.f, 0.f, 0.f);
        float4 s1v = valid ? sp[1] : make_float4(0.f, 0.f, 0.f, 0.f);
        float sv[8] = {s0v.x, s0v.y, s0v.z, s0v.w, s1v.x, s1v.y, s1v.z, s1v.w};
#pragma unroll
        for (int k = 0; k < 8; ++k) {
            int f = FIN + fbase + k;
            smem_f[f * 64 + (n_loc ^ ((f >> 3) & 31))] = sv[k];
        }
    }
    __syncthreads();

    // ---- Phase B: 16 waves, wave w owns j in [16w, 16w+16); lane = node ----
    const int w  = __builtin_amdgcn_readfirstlane(t >> 6);  // 0..15
    const int jb = w * 16;

    float o[16];
#pragma unroll
    for (int i = 0; i < 16; ++i) o[i] = 0.0f;

#pragma unroll 1
    for (int k2 = 0; k2 < 2 * FIN; ++k2) {
        float av = smem_f[k2 * 64 + (l ^ ((k2 >> 3) & 31))];
        const float* wrow = Wt + (size_t)k2 * HID + jb;   // wave-uniform
#pragma unroll
        for (int i = 0; i < 16; ++i) o[i] += av * wrow[i];
    }

    // ---- Epilogue: bias, relu, partials over this wave's 16 j's ----
    float sq = 0.f, g0 = 0.f, g1 = 0.f, r0 = 0.f, r1 = 0.f;
    const float* b1w  = b1  + jb;
    const float* w2la = W2l + jb;
    const float* w2lb = W2l + HID + jb;
    const float* w2ra = W2r + jb;
    const float* w2rb = W2r + HID + jb;
#pragma unroll
    for (int i = 0; i < 16; ++i) {
        float oo = o[i] + b1w[i];
        sq += oo * oo;
        float p = fmaxf(oo, 0.0f);           // relu(o/D) = relu(o)/D
        g0 += p * w2la[i];
        g1 += p * w2lb[i];
        r0 += p * w2ra[i];
        r1 += p * w2rb[i];
    }

    __syncthreads();                          // tile dead; reuse as overlay
    smem_f[0 * 1024 + t] = sq;
    smem_f[1 * 1024 + t] = g0;
    smem_f[2 * 1024 + t] = g1;
    smem_f[3 * 1024 + t] = r0;
    smem_f[4 * 1024 + t] = r1;
    __syncthreads();

    if (t < 64) {
        int n2 = nb + t;
        float sqs = 0.f, G0 = 0.f, G1 = 0.f, R0 = 0.f, R1 = 0.f;
#pragma unroll
        for (int ww = 0; ww < 16; ++ww) {
            sqs += smem_f[0 * 1024 + ww * 64 + t];
            G0  += smem_f[1 * 1024 + ww * 64 + t];
            G1  += smem_f[2 * 1024 + ww * 64 + t];
            R0  += smem_f[3 * 1024 + ww * 64 + t];
            R1  += smem_f[4 * 1024 + ww * 64 + t];
        }
        float inv = 1.0f / fmaxf(sqrtf(sqs), FEPS);
        if (n2 < NN) {
            g[2 * (size_t)n2]     = G0 * inv;
            g[2 * (size_t)n2 + 1] = G1 * inv;
            r[2 * (size_t)n2]     = R0 * inv;
            r[2 * (size_t)n2 + 1] = R1 * inv;
        }
    }
}

// layer-2 mean via CSR gather of g, +b2, +lin_r, L2-normalize, log_softmax
__global__ __launch_bounds__(256) void finalize_kernel(
    const int* __restrict__ off, const int* __restrict__ col,
    const float* __restrict__ g, const float* __restrict__ r,
    const float* __restrict__ b2,
    float* __restrict__ out)
{
    int n = blockIdx.x * 256 + threadIdx.x;
    if (n >= NN) return;
    int s0 = off[n], s1 = off[n + 1];
    float z0 = 0.0f, z1 = 0.0f, y0b = 0.0f, y1b = 0.0f;
    int i = s0;
    for (; i + 1 < s1; i += 2) {
        int sa = clampN(col[i]);
        int sb = clampN(col[i + 1]);
        float2 va = *(const float2*)(g + 2 * (size_t)sa);
        float2 vb = *(const float2*)(g + 2 * (size_t)sb);
        z0 += va.x; z1 += va.y;
        y0b += vb.x; y1b += vb.y;
    }
    if (i < s1) {
        int sa = clampN(col[i]);
        float2 va = *(const float2*)(g + 2 * (size_t)sa);
        z0 += va.x; z1 += va.y;
    }
    z0 += y0b; z1 += y1b;
    float ic = 1.0f / fmaxf((float)(s1 - s0), 1.0f);
    z0 = z0 * ic + b2[0] + r[2 * (size_t)n];
    z1 = z1 * ic + b2[1] + r[2 * (size_t)n + 1];
    float d = 1.0f / fmaxf(sqrtf(z0 * z0 + z1 * z1), FEPS);
    float y0 = z0 * d, y1 = z1 * d;
    float m = fmaxf(y0, y1);
    float l = m + logf(__expf(y0 - m) + __expf(y1 - m));
    out[2 * (size_t)n]     = y0 - l;
    out[2 * (size_t)n + 1] = y1 - l;
}

// ---------------------------------------------------------------------------
extern "C" void kernel_launch(void* const* d_in, const int* in_sizes, int n_in,
                              void* d_out, int out_size, void* d_ws, size_t ws_size,
                              hipStream_t stream) {
    // setup_inputs order: x, edge_index, W1_l, b1, W1_r, W2_l, b2, W2_r
    const float* x   = (const float*)d_in[0];
    const int*   ei  = (const int*)d_in[1];
    const float* W1l = (const float*)d_in[2];
    const float* b1  = (const float*)d_in[3];
    const float* W1r = (const float*)d_in[4];
    const float* W2l = (const float*)d_in[5];
    const float* b2  = (const float*)d_in[6];
    const float* W2r = (const float*)d_in[7];

    const int nsb = (NN + 1023) / 1024;          // 98 scan blocks
    const int ncv = (NN * FIN / 8 + 255) / 256;  // convert blocks
    const int ecb = (NE + 255) / 256;            // edge blocks

    char* p = (char*)d_ws;
    float* Wt = (float*)p;                p += (size_t)256 * 256 * 4;

    size_t need_fast = (size_t)256 * 256 * 4 + (size_t)NN * FIN * 2 +
                       ((size_t)2 * NN + (NN + 1) + NE + 4 * NN + 128) * 4;
    bool fast = (ws_size >= need_fast);   // host-side constant: graph-safe

    __half* xh = nullptr;
    if (fast) { xh = (__half*)p; p += (size_t)NN * FIN * 2; }

    int*   cnt  = (int*)p;
    int*   cur  = cnt + NN;
    int*   off  = cur + NN;                      // NN+1
    int*   col  = off + NN + 1;                  // NE
    float* g    = (float*)(col + NE);            // NN*2
    float* r    = g + 2 * (size_t)NN;            // NN*2
    int*   bsum = (int*)(r + 2 * (size_t)NN);    // 128

    hipMemsetAsync(cnt, 0, 2 * (size_t)NN * sizeof(int), stream);

    int cv = fast ? ncv : 0;
    setup_kernel<<<256 + cv + ecb, 256, 0, stream>>>(ei, x, W1l, W1r, Wt, xh,
                                                     cnt, cv);
    scan_a_kernel<<<nsb, 1024, 0, stream>>>(cnt, off, bsum);
    scan_b_kernel<<<1, 128, 0, stream>>>(bsum, off, nsb);
    scan_c_kernel<<<nsb, 1024, 0, stream>>>(bsum, off);
    fill_kernel<<<ecb, 256, 0, stream>>>(ei, off, cur, col);
    if (fast)
        layer1_kernel<true><<<(NN + 63) / 64, 1024, 0, stream>>>(
            off, col, x, xh, Wt, b1, W2l, W2r, g, r);
    else
        layer1_kernel<false><<<(NN + 63) / 64, 1024, 0, stream>>>(
            off, col, x, xh, Wt, b1, W2l, W2r, g, r);
    finalize_kernel<<<(NN + 255) / 256, 256, 0, stream>>>(off, col, g, r, b2,
                                                          (float*)d_out);
}